// Round 1
// baseline (443.338 us; speedup 1.0000x reference)
//
#include <hip/hip_runtime.h>
#include <hip/hip_bf16.h>

#define CIN   64
#define COUT  64
#define TT    512
#define FF    161
#define KTOT  576          // 9 * 64
#define TFSTR (TT*FF)      // 82432

typedef __bf16 bf16x8 __attribute__((ext_vector_type(8)));
typedef float  f32x4  __attribute__((ext_vector_type(4)));

__device__ __forceinline__ unsigned short f2bf(float v) {
    union { float f; unsigned int u; } c; c.f = v;
    unsigned int u = c.u + 0x7FFFu + ((c.u >> 16) & 1u);   // RNE
    return (unsigned short)(u >> 16);
}

// Repack: W2[f][o][k], k = (dm*3+dn)*64 + i  (bf16)
// Thread index enumerates source order (o,i,f,q) -> fully coalesced reads;
// scattered 2B writes stay resident in L2 (total 11.9 MB < 32 MB).
__global__ __launch_bounds__(256) void prep_weights(
    const float* __restrict__ ksrc, unsigned short* __restrict__ w2)
{
    int idx = blockIdx.x * 256 + threadIdx.x;   // exact multiple, no guard needed
    int q = idx % 9;
    int t = idx / 9;
    int f = t % FF;  t /= FF;
    int i = t % CIN;
    int o = t / CIN;
    float v = ksrc[idx];
    w2[(f*COUT + o)*KTOT + q*64 + i] = f2bf(v);
}

// Block: 4 waves = 256 threads. Wave w handles frequency f = f0 + w.
// Block tile: 64 t (one b) x 64 o for 4 consecutive f.
// LDS: x halo tile [fl 0..5][tl 0..65][i 0..63] bf16, XOR-swizzled in i.
__global__ __launch_bounds__(256) void conv_mfma(
    const float* __restrict__ x, const unsigned short* __restrict__ w2,
    const float* __restrict__ bias, float* __restrict__ out)
{
    // XCD-bijective swizzle: all 41 f-blocks of one (b,t-tile) group land on
    // the same XCD (blockIdx.x % 8 stays constant within a group) so output
    // lines (16 f values each) merge in that XCD's L2.
    int bx = blockIdx.x;            // 2624 = 8 * 41 * 8 blocks
    int r  = bx & 7;
    int q  = bx >> 3;               // 0..327
    int fblk = q % 41;
    int g  = (q / 41) * 8 + r;      // 0..63 : (b, t-tile)
    int b  = g >> 3;
    int t0 = (g & 7) * 64;
    int f0 = fblk * 4;

    __shared__ unsigned short As[6][66][64];   // 50,688 B

    int tid = threadIdx.x;

    // ---- stage x halo tile: gt in [t0-1, t0+64], gf in [f0-1, f0+4] ----
    for (int i = 0; i < 64; i += 4) {
        #pragma unroll
        for (int pp = 0; pp < 2; ++pp) {
            int p = tid + pp*256;
            if (p < 396) {                       // 66 * 6
                int tl = p / 6, fl = p % 6;
                int gt = t0 - 1 + tl;
                int gf = f0 - 1 + fl;
                bool ok = (gt >= 0) && (gt < TT) && (gf >= 0) && (gf < FF);
                const float* xp = x + (((b*CIN + i)*TT + gt)*FF + gf);
                float v0 = ok ? xp[0]       : 0.f;
                float v1 = ok ? xp[TFSTR]   : 0.f;
                float v2 = ok ? xp[2*TFSTR] : 0.f;
                float v3 = ok ? xp[3*TFSTR] : 0.f;
                int isw = i ^ (((tl + fl) & 7) << 3);   // XOR swizzle (8-elem blocks)
                ushort4 pk;
                pk.x = f2bf(v0); pk.y = f2bf(v1); pk.z = f2bf(v2); pk.w = f2bf(v3);
                *reinterpret_cast<ushort4*>(&As[fl][tl][isw]) = pk;
            }
        }
    }
    __syncthreads();

    int wv = tid >> 6;          // wave id 0..3
    int l  = tid & 63;
    int f  = f0 + wv;
    if (f >= FF) return;        // dead wave on the last f-block (no barriers after)

    int l15 = l & 15;
    int lq  = l >> 4;

    f32x4 acc[4][4] = {};       // M-frag x N-frag, fp32 accumulate

    const unsigned short* wb = w2 + (size_t)f * (COUT * KTOT);

    #pragma unroll
    for (int dm = 0; dm < 3; ++dm) {
        #pragma unroll
        for (int dn = 0; dn < 3; ++dn) {
            int fl = wv + dn;
            int kq = (dm*3 + dn) * 64;
            #pragma unroll
            for (int is = 0; is < 2; ++is) {
                int i0 = is*32 + lq*8;          // lane's 8-wide k block within tap
                bf16x8 a[4];
                #pragma unroll
                for (int mf = 0; mf < 4; ++mf) {
                    int tl  = mf*16 + l15 + dm;
                    int isw = i0 ^ (((tl + fl) & 7) << 3);
                    a[mf] = *reinterpret_cast<const bf16x8*>(&As[fl][tl][isw]);
                }
                int kb = kq + i0;
                #pragma unroll
                for (int nf = 0; nf < 4; ++nf) {
                    bf16x8 bfr = *reinterpret_cast<const bf16x8*>(
                        &wb[(size_t)(nf*16 + l15) * KTOT + kb]);
                    #pragma unroll
                    for (int mf = 0; mf < 4; ++mf)
                        acc[mf][nf] = __builtin_amdgcn_mfma_f32_16x16x32_bf16(
                            a[mf], bfr, acc[mf][nf], 0, 0, 0);
                }
            }
        }
    }

    // ---- epilogue: bias + store (4B scattered; f fixed per wave) ----
    #pragma unroll
    for (int nf = 0; nf < 4; ++nf) {
        int o = nf*16 + l15;
        float bv = bias[o*FF + f];
        size_t obase = (((size_t)b*COUT + o)*TT + t0 + lq*4)*FF + f;
        #pragma unroll
        for (int mf = 0; mf < 4; ++mf) {
            #pragma unroll
            for (int rr = 0; rr < 4; ++rr) {
                out[obase + (size_t)(mf*16 + rr)*FF] = acc[mf][nf][rr] + bv;
            }
        }
    }
}

extern "C" void kernel_launch(void* const* d_in, const int* in_sizes, int n_in,
                              void* d_out, int out_size, void* d_ws, size_t ws_size,
                              hipStream_t stream)
{
    (void)in_sizes; (void)n_in; (void)out_size; (void)ws_size;
    const float* x    = (const float*)d_in[0];
    const float* k    = (const float*)d_in[1];
    const float* bias = (const float*)d_in[2];
    float* out = (float*)d_out;
    unsigned short* w2 = (unsigned short*)d_ws;   // 161*64*576*2 = 11,870,208 B

    prep_weights<<<(FF*COUT*KTOT)/256, 256, 0, stream>>>(k, w2);   // 23184 blocks
    conv_mfma<<<8*41*8, 256, 0, stream>>>(x, w2, bias, out);       // 2624 blocks
}

// Round 2
// 433.848 us; speedup vs baseline: 1.0219x; 1.0219x over previous
//
#include <hip/hip_runtime.h>
#include <hip/hip_bf16.h>

#define CIN   64
#define COUT  64
#define TT    512
#define FF    161
#define KTOT  576          // 9 * 64
#define TFSTR (TT*FF)      // 82432
#define FP_   168          // padded f dim of X2: fp = f+1, zeros at fp=0 and fp>=162

#define W2_BYTES ((size_t)FF*COUT*KTOT*2)            // 11,870,208
#define X2_BYTES ((size_t)8*TT*FP_*64*2)             // 88,080,384

typedef __bf16 bf16x8 __attribute__((ext_vector_type(8)));
typedef float  f32x4  __attribute__((ext_vector_type(4)));
typedef unsigned short u16x8 __attribute__((ext_vector_type(8)));

__device__ __forceinline__ unsigned short f2bf(float v) {
    union { float f; unsigned int u; } c; c.f = v;
    unsigned int u = c.u + 0x7FFFu + ((c.u >> 16) & 1u);   // RNE
    return (unsigned short)(u >> 16);
}

// ---------------- weights: W2[f][o][k], k=(dm*3+dn)*64+i (bf16) ----------------
__global__ __launch_bounds__(256) void prep_weights(
    const float* __restrict__ ksrc, unsigned short* __restrict__ w2)
{
    int idx = blockIdx.x * 256 + threadIdx.x;
    int q = idx % 9;
    int t = idx / 9;
    int f = t % FF;  t /= FF;
    int i = t % CIN;
    int o = t / CIN;
    float v = ksrc[idx];
    w2[(f*COUT + o)*KTOT + q*64 + i] = f2bf(v);
}

// ---------------- x: (b,i,t,f) f32  ->  X2[b][t][fp][i] bf16, fp=f+1 ----------------
// one block per (b,t); coalesced 644B-run reads, LDS transpose, contiguous 16B stores
__global__ __launch_bounds__(256) void prep_x(
    const float* __restrict__ x, unsigned short* __restrict__ x2)
{
    int bt = blockIdx.x;            // 0..4095
    int b  = bt >> 9;
    int t  = bt & 511;
    __shared__ unsigned short Xs[FF][72];   // 23,184 B (pad 72 -> 16B-aligned rows)

    int tid = threadIdx.x;
    const float* xb = x + (size_t)b*CIN*TFSTR + (size_t)t*FF;
    #pragma unroll 4
    for (int k = 0; k < 41; ++k) {
        int e = tid + k*256;
        if (e < CIN*FF) {
            int i = e / FF;
            int f = e - i*FF;
            Xs[f][i] = f2bf(xb[(size_t)i*TFSTR + f]);
        }
    }
    __syncthreads();
    unsigned short* ob = x2 + (size_t)bt * FP_ * 64;
    #pragma unroll
    for (int k = 0; k < 6; ++k) {
        int p   = tid + k*256;
        int row = p >> 3;           // fp
        int j   = p & 7;
        if (row < FP_) {
            u16x8 v = {0,0,0,0,0,0,0,0};
            if (row >= 1 && row <= FF) v = *(const u16x8*)&Xs[row-1][j*8];
            *(u16x8*)&ob[row*64 + j*8] = v;
        }
    }
}

// ---------------- main: 4 waves, wave w -> f = f0+w; 64t x 64o per block ----------------
__global__ __launch_bounds__(256) void conv_mfma2(
    const unsigned short* __restrict__ x2, const unsigned short* __restrict__ w2,
    const float* __restrict__ bias, float* __restrict__ out)
{
    int bx = blockIdx.x;            // 2624 = 8*41*8
    int r  = bx & 7;
    int q  = bx >> 3;
    int fblk = q % 41;              // consecutive XCD-local blocks share g, walk fblk
    int g  = (q / 41) * 8 + r;
    int b  = g >> 3;
    int t0 = (g & 7) * 64;
    int f0 = fblk * 4;

    // LDS: rows = tl*6+fl (tl 0..65, fl 0..5), padded to 416 rows of 64 bf16
    __shared__ alignas(16) unsigned short As[416*64];   // 53,248 B

    int tid = threadIdx.x;
    int wv  = tid >> 6;
    int l   = tid & 63;
    int lr  = l >> 3;
    int j   = l & 7;

    const unsigned short* zrow = x2 + 167*64;   // (b=0,t=0,fp=167): guaranteed zeros

    #pragma unroll
    for (int it = 0; it < 13; ++it) {
        int r0  = wv*8 + it*32;                 // wave-uniform LDS row base
        int row = r0 + lr;
        int tl  = row / 6;
        int fl  = row - tl*6;
        int gt  = t0 - 1 + tl;
        int fp  = f0 + fl;                      // <= 165 < FP_
        bool ok = (tl < 66) && (gt >= 0) && (gt < TT);
        int key = (tl + fl) & 7;
        const unsigned short* src = ok
            ? x2 + ((((size_t)b*TT + gt)*FP_ + fp)*64 + ((j ^ key) * 8))
            : zrow + j*8;
        __builtin_amdgcn_global_load_lds(
            (const __attribute__((address_space(1))) void*)src,
            (__attribute__((address_space(3))) void*)(As + (size_t)r0*64),
            16, 0, 0);
    }
    __syncthreads();

    int f = f0 + wv;
    if (f >= FF) return;            // dead waves only on last fblk; no barriers below

    int l15 = l & 15;
    int lq  = l >> 4;

    f32x4 acc[4][4] = {};
    const unsigned short* wb = w2 + (size_t)f * (COUT * KTOT);

    #pragma unroll
    for (int dm = 0; dm < 3; ++dm) {
        #pragma unroll
        for (int dn = 0; dn < 3; ++dn) {
            int fl = wv + dn;
            int kq = (dm*3 + dn) * 64;
            #pragma unroll
            for (int is = 0; is < 2; ++is) {
                int i0 = is*32 + lq*8;
                bf16x8 a[4];
                #pragma unroll
                for (int mf = 0; mf < 4; ++mf) {
                    int tl  = mf*16 + l15 + dm;
                    int isw = i0 ^ (((tl + fl) & 7) << 3);
                    a[mf] = *(const bf16x8*)&As[(tl*6 + fl)*64 + isw];
                }
                int kb = kq + i0;
                #pragma unroll
                for (int nf = 0; nf < 4; ++nf) {
                    bf16x8 bfr = *(const bf16x8*)&wb[(size_t)(nf*16 + l15) * KTOT + kb];
                    #pragma unroll
                    for (int mf = 0; mf < 4; ++mf)
                        acc[mf][nf] = __builtin_amdgcn_mfma_f32_16x16x32_bf16(
                            a[mf], bfr, acc[mf][nf], 0, 0, 0);
                }
            }
        }
    }

    #pragma unroll
    for (int nf = 0; nf < 4; ++nf) {
        int o = nf*16 + l15;
        float bv = bias[o*FF + f];
        size_t obase = (((size_t)b*COUT + o)*TT + t0 + lq*4)*FF + f;
        #pragma unroll
        for (int mf = 0; mf < 4; ++mf)
            #pragma unroll
            for (int rr = 0; rr < 4; ++rr)
                out[obase + (size_t)(mf*16 + rr)*FF] = acc[mf][nf][rr] + bv;
    }
}

// ---------------- round-1 fallback (stages directly from f32 x) ----------------
__global__ __launch_bounds__(256) void conv_mfma(
    const float* __restrict__ x, const unsigned short* __restrict__ w2,
    const float* __restrict__ bias, float* __restrict__ out)
{
    int bx = blockIdx.x;
    int r  = bx & 7;
    int q  = bx >> 3;
    int fblk = q % 41;
    int g  = (q / 41) * 8 + r;
    int b  = g >> 3;
    int t0 = (g & 7) * 64;
    int f0 = fblk * 4;

    __shared__ unsigned short Bs[6][66][64];
    int tid = threadIdx.x;

    for (int i = 0; i < 64; i += 4) {
        #pragma unroll
        for (int pp = 0; pp < 2; ++pp) {
            int p = tid + pp*256;
            if (p < 396) {
                int tl = p / 6, fl = p % 6;
                int gt = t0 - 1 + tl;
                int gf = f0 - 1 + fl;
                bool ok = (gt >= 0) && (gt < TT) && (gf >= 0) && (gf < FF);
                const float* xp = x + (((size_t)(b*CIN + i)*TT + gt)*FF + gf);
                float v0 = ok ? xp[0]       : 0.f;
                float v1 = ok ? xp[TFSTR]   : 0.f;
                float v2 = ok ? xp[2*TFSTR] : 0.f;
                float v3 = ok ? xp[3*TFSTR] : 0.f;
                int isw = i ^ (((tl + fl) & 7) << 3);
                ushort4 pk;
                pk.x = f2bf(v0); pk.y = f2bf(v1); pk.z = f2bf(v2); pk.w = f2bf(v3);
                *reinterpret_cast<ushort4*>(&Bs[fl][tl][isw]) = pk;
            }
        }
    }
    __syncthreads();

    int wv = tid >> 6;
    int l  = tid & 63;
    int f  = f0 + wv;
    if (f >= FF) return;

    int l15 = l & 15;
    int lq  = l >> 4;
    f32x4 acc[4][4] = {};
    const unsigned short* wb = w2 + (size_t)f * (COUT * KTOT);

    #pragma unroll
    for (int dm = 0; dm < 3; ++dm)
    #pragma unroll
    for (int dn = 0; dn < 3; ++dn) {
        int fl = wv + dn;
        int kq = (dm*3 + dn) * 64;
        #pragma unroll
        for (int is = 0; is < 2; ++is) {
            int i0 = is*32 + lq*8;
            bf16x8 a[4];
            #pragma unroll
            for (int mf = 0; mf < 4; ++mf) {
                int tl  = mf*16 + l15 + dm;
                int isw = i0 ^ (((tl + fl) & 7) << 3);
                a[mf] = *(const bf16x8*)&Bs[fl][tl][isw];
            }
            int kb = kq + i0;
            #pragma unroll
            for (int nf = 0; nf < 4; ++nf) {
                bf16x8 bfr = *(const bf16x8*)&wb[(size_t)(nf*16 + l15) * KTOT + kb];
                #pragma unroll
                for (int mf = 0; mf < 4; ++mf)
                    acc[mf][nf] = __builtin_amdgcn_mfma_f32_16x16x32_bf16(
                        a[mf], bfr, acc[mf][nf], 0, 0, 0);
            }
        }
    }

    #pragma unroll
    for (int nf = 0; nf < 4; ++nf) {
        int o = nf*16 + l15;
        float bv = bias[o*FF + f];
        size_t obase = (((size_t)b*COUT + o)*TT + t0 + lq*4)*FF + f;
        #pragma unroll
        for (int mf = 0; mf < 4; ++mf)
            #pragma unroll
            for (int rr = 0; rr < 4; ++rr)
                out[obase + (size_t)(mf*16 + rr)*FF] = acc[mf][nf][rr] + bv;
    }
}

extern "C" void kernel_launch(void* const* d_in, const int* in_sizes, int n_in,
                              void* d_out, int out_size, void* d_ws, size_t ws_size,
                              hipStream_t stream)
{
    (void)in_sizes; (void)n_in; (void)out_size;
    const float* x    = (const float*)d_in[0];
    const float* k    = (const float*)d_in[1];
    const float* bias = (const float*)d_in[2];
    float* out = (float*)d_out;
    unsigned short* w2 = (unsigned short*)d_ws;

    prep_weights<<<(FF*COUT*KTOT)/256, 256, 0, stream>>>(k, w2);   // 23184 blocks

    if (ws_size >= W2_BYTES + X2_BYTES) {
        unsigned short* x2 = (unsigned short*)((char*)d_ws + W2_BYTES);  // 16B-aligned
        prep_x<<<8*TT, 256, 0, stream>>>(x, x2);                    // 4096 blocks
        conv_mfma2<<<8*41*8, 256, 0, stream>>>(x2, w2, bias, out);  // 2624 blocks
    } else {
        conv_mfma<<<8*41*8, 256, 0, stream>>>(x, w2, bias, out);    // fallback
    }
}

// Round 3
// 367.500 us; speedup vs baseline: 1.2064x; 1.1805x over previous
//
#include <hip/hip_runtime.h>
#include <hip/hip_bf16.h>

#define CIN   64
#define COUT  64
#define TT    512
#define FF    161
#define KTOT  576          // 9 * 64
#define TFSTR (TT*FF)      // 82432
#define FP_   168          // padded f dim of X2: fp = f+1, zeros at fp=0 and fp>=162
#define WROW  (COUT*KTOT)  // 36864 shorts per f

#define W2_BYTES ((size_t)FF*COUT*KTOT*2)            // 11,870,208
#define X2_BYTES ((size_t)8*TT*FP_*64*2)             // 88,080,384

typedef __bf16 bf16x8 __attribute__((ext_vector_type(8)));
typedef float  f32x4  __attribute__((ext_vector_type(4)));
typedef unsigned short u16x8 __attribute__((ext_vector_type(8)));
// reduced-alignment vectors (gfx9+ allows dword-aligned multi-dword ops)
typedef float f4u __attribute__((ext_vector_type(4), aligned(4)));
typedef float f2u __attribute__((ext_vector_type(2), aligned(4)));

__device__ __forceinline__ unsigned short f2bf(float v) {
    union { float f; unsigned int u; } c; c.f = v;
    unsigned int u = c.u + 0x7FFFu + ((c.u >> 16) & 1u);   // RNE
    return (unsigned short)(u >> 16);
}

// ---------------- weights: W2[f][o][k], k=(dm*3+dn)*64+i (bf16) ----------------
__global__ __launch_bounds__(256) void prep_weights(
    const float* __restrict__ ksrc, unsigned short* __restrict__ w2)
{
    int idx = blockIdx.x * 256 + threadIdx.x;
    int q = idx % 9;
    int t = idx / 9;
    int f = t % FF;  t /= FF;
    int i = t % CIN;
    int o = t / CIN;
    float v = ksrc[idx];
    w2[(f*COUT + o)*KTOT + q*64 + i] = f2bf(v);
}

// ---------------- x: (b,i,t,f) f32  ->  X2[b][t][fp][i] bf16, fp=f+1 ----------------
// phase1: float2 coalesced reads -> Xs[i][f] (packed b32 writes, conflict-free)
// phase2: per-thread 8x u16 column gather -> one 16B contiguous store per row-chunk
__global__ __launch_bounds__(256) void prep_x(
    const float* __restrict__ x, unsigned short* __restrict__ x2)
{
    int bt = blockIdx.x;            // 0..4095
    int b  = bt >> 9;
    int t  = bt & 511;
    __shared__ unsigned short Xs[64][170];   // 21,760 B; stride 170 -> 2-way-ish banks

    int tid = threadIdx.x;
    const float* xb = x + (size_t)b*CIN*TFSTR + (size_t)t*FF;

    #pragma unroll
    for (int k = 0; k < 21; ++k) {
        int s = tid + k*256;
        if (s < 5184) {                      // 64 i * 81 slots (80 float2 + 1 tail)
            int i = s / 81;
            int u = s - i*81;
            const float* p = xb + (size_t)i*TFSTR + 2*u;
            if (u < 80) {
                f2u v = *(const f2u*)p;
                unsigned pk = (unsigned)f2bf(v.x) | ((unsigned)f2bf(v.y) << 16);
                *(unsigned*)&Xs[i][2*u] = pk;
            } else {
                Xs[i][160] = f2bf(*p);
            }
        }
    }
    __syncthreads();

    unsigned short* ob = x2 + (size_t)bt * FP_ * 64;
    #pragma unroll
    for (int k = 0; k < 6; ++k) {
        int s = tid + k*256;
        if (s < 1344) {                      // 168 fp rows * 8 chunks
            int fp = s >> 3;
            int j  = s & 7;
            u16x8 v = {0,0,0,0,0,0,0,0};
            if (fp >= 1 && fp < 162) {
                int f = fp - 1;
                #pragma unroll
                for (int e = 0; e < 8; ++e) v[e] = Xs[j*8 + e][f];
            }
            *(u16x8*)&ob[fp*64 + j*8] = v;
        }
    }
}

// ---------------- main: 4 waves; wave = o-quarter; acc over 4 f in registers ----------------
// block tile: 4 f x 64 o x 64 t. Epilogue: direct 16B f-contiguous stores (no transpose).
__global__ __launch_bounds__(256, 2) void conv_mfma3(
    const unsigned short* __restrict__ x2, const unsigned short* __restrict__ w2,
    const float* __restrict__ bias, float* __restrict__ out)
{
    // XCD mapping: per XCD iterate fblk-QUADS (16 f = one 64B out line) with same g
    // adjacent -> L2 write-merge + 1.18MB weight quad stays L2-hot.
    int bx  = blockIdx.x;           // 2624 = 8 * 328
    int xcd = bx & 7;
    int s   = bx >> 3;              // 0..327
    int fblk, g;
    if (s < 320) {
        int qd = s >> 5, w = s & 31;
        fblk = qd*4 + (w & 3);      // quad member adjacent in dispatch
        g    = (w >> 2)*8 + xcd;
    } else {
        fblk = 40;                  // f0=160 (single valid f)
        g    = (s - 320)*8 + xcd;
    }
    int b  = g >> 3;
    int t0 = (g & 7) * 64;
    int f0 = fblk * 4;

    // LDS rows = tl*6+fl (tl 0..65, fl 0..5), padded to 416 rows of 64 bf16
    __shared__ alignas(16) unsigned short As[416*64];   // 53,248 B -> 2 blocks/CU

    int tid = threadIdx.x;
    int wv  = tid >> 6;             // o-quarter
    int l   = tid & 63;
    int lr  = l >> 3;
    int j   = l & 7;

    const unsigned short* zrow = x2 + 167*64;   // (b=0,t=0,fp=167): guaranteed zeros

    #pragma unroll
    for (int it = 0; it < 13; ++it) {
        int r0  = wv*8 + it*32;
        int row = r0 + lr;
        int tl  = row / 6;
        int fl  = row - tl*6;
        int gt  = t0 - 1 + tl;
        int fp  = f0 + fl;                      // <= 165 < FP_
        bool ok = (tl < 66) && (gt >= 0) && (gt < TT);
        int key = (tl + fl) & 7;
        const unsigned short* src = ok
            ? x2 + ((((size_t)b*TT + gt)*FP_ + fp)*64 + ((j ^ key) * 8))
            : zrow + j*8;
        __builtin_amdgcn_global_load_lds(
            (const __attribute__((address_space(1))) void*)src,
            (__attribute__((address_space(3))) void*)(As + (size_t)r0*64),
            16, 0, 0);
    }
    __syncthreads();

    int l15 = l & 15;
    int lq  = l >> 4;
    int o   = wv*16 + l15;

    f32x4 acc[4][4] = {};           // [ff][mf]
    const unsigned short* wb = w2 + ((size_t)f0*COUT + o)*KTOT;
    // (fblk==40, ff>=1 reads run past w2 into x2 region inside d_ws: safe, discarded)

    #pragma unroll
    for (int dm = 0; dm < 3; ++dm) {
        #pragma unroll
        for (int is = 0; is < 2; ++is) {
            int kb = is*32 + lq*8;
            bf16x8 bfr[3][4];
            #pragma unroll
            for (int dn = 0; dn < 3; ++dn)
                #pragma unroll
                for (int ff = 0; ff < 4; ++ff)
                    bfr[dn][ff] = *(const bf16x8*)&wb[(size_t)ff*WROW + (dm*3+dn)*64 + kb];
            #pragma unroll
            for (int mf = 0; mf < 4; ++mf) {
                int tl = mf*16 + l15 + dm;
                bf16x8 a6[6];
                #pragma unroll
                for (int u = 0; u < 6; ++u) {
                    int isw = kb ^ (((tl + u) & 7) << 3);
                    a6[u] = *(const bf16x8*)&As[(tl*6 + u)*64 + isw];
                }
                #pragma unroll
                for (int dn = 0; dn < 3; ++dn)
                    #pragma unroll
                    for (int ff = 0; ff < 4; ++ff)
                        acc[ff][mf] = __builtin_amdgcn_mfma_f32_16x16x32_bf16(
                            a6[ff + dn], bfr[dn][ff], acc[ff][mf], 0, 0, 0);
            }
        }
    }

    // ---- epilogue: bias + f-contiguous 16B stores straight from registers ----
    float bv[4];
    #pragma unroll
    for (int ff = 0; ff < 4; ++ff) {
        int fb = f0 + ff; if (fb > FF-1) fb = FF-1;     // clamp (fblk 40)
        bv[ff] = bias[o*FF + fb];
    }
    size_t orow = ((size_t)b*COUT + o)*TT + t0;
    if (f0 + 3 < FF) {
        #pragma unroll
        for (int mf = 0; mf < 4; ++mf)
            #pragma unroll
            for (int rr = 0; rr < 4; ++rr) {
                int t = mf*16 + lq*4 + rr;
                f4u v = { acc[0][mf][rr] + bv[0], acc[1][mf][rr] + bv[1],
                          acc[2][mf][rr] + bv[2], acc[3][mf][rr] + bv[3] };
                *(f4u*)(out + (orow + t)*FF + f0) = v;
            }
    } else {
        #pragma unroll
        for (int mf = 0; mf < 4; ++mf)
            #pragma unroll
            for (int rr = 0; rr < 4; ++rr) {
                int t = mf*16 + lq*4 + rr;
                out[(orow + t)*FF + (FF-1)] = acc[0][mf][rr] + bv[0];
            }
    }
}

// ---------------- round-1 fallback (stages directly from f32 x; needs only w2) ----------------
__global__ __launch_bounds__(256) void conv_mfma(
    const float* __restrict__ x, const unsigned short* __restrict__ w2,
    const float* __restrict__ bias, float* __restrict__ out)
{
    int bx = blockIdx.x;
    int r  = bx & 7;
    int q  = bx >> 3;
    int fblk = q % 41;
    int g  = (q / 41) * 8 + r;
    int b  = g >> 3;
    int t0 = (g & 7) * 64;
    int f0 = fblk * 4;

    __shared__ unsigned short Bs[6][66][64];
    int tid = threadIdx.x;

    for (int i = 0; i < 64; i += 4) {
        #pragma unroll
        for (int pp = 0; pp < 2; ++pp) {
            int p = tid + pp*256;
            if (p < 396) {
                int tl = p / 6, fl = p % 6;
                int gt = t0 - 1 + tl;
                int gf = f0 - 1 + fl;
                bool ok = (gt >= 0) && (gt < TT) && (gf >= 0) && (gf < FF);
                const float* xp = x + (((size_t)(b*CIN + i)*TT + gt)*FF + gf);
                float v0 = ok ? xp[0]       : 0.f;
                float v1 = ok ? xp[TFSTR]   : 0.f;
                float v2 = ok ? xp[2*TFSTR] : 0.f;
                float v3 = ok ? xp[3*TFSTR] : 0.f;
                int isw = i ^ (((tl + fl) & 7) << 3);
                ushort4 pk;
                pk.x = f2bf(v0); pk.y = f2bf(v1); pk.z = f2bf(v2); pk.w = f2bf(v3);
                *reinterpret_cast<ushort4*>(&Bs[fl][tl][isw]) = pk;
            }
        }
    }
    __syncthreads();

    int wv = tid >> 6;
    int l  = tid & 63;
    int f  = f0 + wv;
    if (f >= FF) return;

    int l15 = l & 15;
    int lq  = l >> 4;
    f32x4 acc[4][4] = {};
    const unsigned short* wb = w2 + (size_t)f * (COUT * KTOT);

    #pragma unroll
    for (int dm = 0; dm < 3; ++dm)
    #pragma unroll
    for (int dn = 0; dn < 3; ++dn) {
        int fl = wv + dn;
        int kq = (dm*3 + dn) * 64;
        #pragma unroll
        for (int is = 0; is < 2; ++is) {
            int i0 = is*32 + lq*8;
            bf16x8 a[4];
            #pragma unroll
            for (int mf = 0; mf < 4; ++mf) {
                int tl  = mf*16 + l15 + dm;
                int isw = i0 ^ (((tl + fl) & 7) << 3);
                a[mf] = *(const bf16x8*)&Bs[fl][tl][isw];
            }
            int kb = kq + i0;
            #pragma unroll
            for (int nf = 0; nf < 4; ++nf) {
                bf16x8 bfr = *(const bf16x8*)&wb[(size_t)(nf*16 + l15) * KTOT + kb];
                #pragma unroll
                for (int mf = 0; mf < 4; ++mf)
                    acc[mf][nf] = __builtin_amdgcn_mfma_f32_16x16x32_bf16(
                        a[mf], bfr, acc[mf][nf], 0, 0, 0);
            }
        }
    }

    #pragma unroll
    for (int nf = 0; nf < 4; ++nf) {
        int o = nf*16 + l15;
        float bv = bias[o*FF + f];
        size_t obase = (((size_t)b*COUT + o)*TT + t0 + lq*4)*FF + f;
        #pragma unroll
        for (int mf = 0; mf < 4; ++mf)
            #pragma unroll
            for (int rr = 0; rr < 4; ++rr)
                out[obase + (size_t)(mf*16 + rr)*FF] = acc[mf][nf][rr] + bv;
    }
}

extern "C" void kernel_launch(void* const* d_in, const int* in_sizes, int n_in,
                              void* d_out, int out_size, void* d_ws, size_t ws_size,
                              hipStream_t stream)
{
    (void)in_sizes; (void)n_in; (void)out_size;
    const float* x    = (const float*)d_in[0];
    const float* k    = (const float*)d_in[1];
    const float* bias = (const float*)d_in[2];
    float* out = (float*)d_out;
    unsigned short* w2 = (unsigned short*)d_ws;

    prep_weights<<<(FF*COUT*KTOT)/256, 256, 0, stream>>>(k, w2);   // 23184 blocks

    if (ws_size >= W2_BYTES + X2_BYTES) {
        unsigned short* x2 = (unsigned short*)((char*)d_ws + W2_BYTES);  // 16B-aligned
        prep_x<<<8*TT, 256, 0, stream>>>(x, x2);                    // 4096 blocks
        conv_mfma3<<<8*328, 256, 0, stream>>>(x2, w2, bias, out);   // 2624 blocks
    } else {
        conv_mfma<<<8*41*8, 256, 0, stream>>>(x, w2, bias, out);    // fallback
    }
}